// Round 13
// baseline (333.450 us; speedup 1.0000x reference)
//
#include <hip/hip_runtime.h>
#include <math.h>

#define NN 30000
#define NE 480000
#define NG 10
#define TB 8192          // radial table bins over [0, 4.0]
#define NBS 118          // ceil(NN / 256) scan blocks

typedef __attribute__((ext_vector_type(4))) float f32x4;
typedef __attribute__((ext_vector_type(8))) _Float16 half8;

__device__ __forceinline__ float h2f(ushort u) {
    _Float16 h; __builtin_memcpy(&h, &u, 2); return (float)h;
}
__device__ __forceinline__ ushort f2h(float f) {
    _Float16 h = (_Float16)f; ushort u; __builtin_memcpy(&u, &h, 2); return u;
}
__device__ __forceinline__ unsigned int pack2h(float a, float b) {
    return (unsigned int)f2h(a) | ((unsigned int)f2h(b) << 16);
}
struct F8 { float v0,v1,v2,v3,v4,v5,v6,v7; };
__device__ __forceinline__ F8 unpack8h(uint4 v) {
    F8 r;
    r.v0 = h2f((ushort)(v.x & 0xffffu)); r.v1 = h2f((ushort)(v.x >> 16));
    r.v2 = h2f((ushort)(v.y & 0xffffu)); r.v3 = h2f((ushort)(v.y >> 16));
    r.v4 = h2f((ushort)(v.z & 0xffffu)); r.v5 = h2f((ushort)(v.z >> 16));
    r.v6 = h2f((ushort)(v.w & 0xffffu)); r.v7 = h2f((ushort)(v.w >> 16));
    return r;
}
__device__ __forceinline__ float rcpf(float x) { return __builtin_amdgcn_rcpf(x); }
__device__ __forceinline__ float fast_tanh(float x) {
    return 1.0f - 2.0f * rcpf(__expf(2.0f * x) + 1.0f);
}

// ---------------------------------------------------------------------------
// Radial table: tab[i][ii][l] = q_l(r_i)[ii],  r_i = i * 4/TB
// ---------------------------------------------------------------------------
__global__ __launch_bounds__(256) void build_table_kernel(
    const float* __restrict__ fc1, const float* __restrict__ b1,
    const float* __restrict__ fc2, float* __restrict__ tab)
{
    __shared__ float sF1[4000];
    __shared__ float sF2[4000];
    __shared__ float sB[400];
    int tid = threadIdx.x;
    for (int i = tid; i < 4000; i += 256) { sF1[i] = fc1[i]; sF2[i] = fc2[i]; }
    for (int i = tid; i < 400; i += 256) sB[i] = b1[i];
    __syncthreads();

    int id = blockIdx.x * 256 + tid;
    if (id >= (TB + 1) * 16) return;
    int jc = id & 3, l = (id >> 2) & 3, i = id >> 4;
    float r = (float)i * (4.0f / TB);

    float emb[10];
    const float C = 26.6692991f;   // 1.14136 * e^2 * sqrt(10)
    float rr = r * 2.75f;
    #pragma unroll
    for (int k = 0; k < 10; k++) {
        float dd = rr - (float)(k + 1);
        float d2 = dd * dd;
        emb[k] = (d2 < 1.0f) ? C * __expf(-rcpf(1.0f - d2)) : 0.0f;
    }

    const float* __restrict__ F1 = sF1 + l * 1000;   // [10][100]
    const float* __restrict__ Bv = sB + l * 100;
    const float* __restrict__ F2 = sF2 + l * 1000;   // [100][10]
    float q[10] = {0,0,0,0,0,0,0,0,0,0};
    int j0 = jc * 25;
    for (int j = j0; j < j0 + 25; j++) {
        float h = Bv[j];
        #pragma unroll
        for (int k = 0; k < 10; k++) h = fmaf(emb[k], F1[k * 100 + j], h);
        float s = h * rcpf(1.0f + __expf(-h));   // silu
        #pragma unroll
        for (int k = 0; k < 10; k++) q[k] = fmaf(s, F2[j * 10 + k], q[k]);
    }
    #pragma unroll
    for (int k = 0; k < 10; k++) {
        q[k] += __shfl_xor(q[k], 1);
        q[k] += __shfl_xor(q[k], 2);
    }
    if (jc == 0) {
        #pragma unroll
        for (int k = 0; k < 10; k++) tab[(size_t)i * 40 + k * 4 + l] = q[k];
    }
}

// both weight transposes in one launch: WT[n][k] = fp16(W[k][n])
__global__ void transw2_kernel(const float* __restrict__ W1, const float* __restrict__ W2,
                               ushort* __restrict__ WT1, ushort* __restrict__ WT2)
{
    int id = blockIdx.x * 256 + threadIdx.x;
    if (id >= 2 * 288 * 288) return;
    int which = id >= 288 * 288;
    int i = which ? id - 288 * 288 : id;
    int n = i / 288, k = i - n * 288;
    if (which) WT2[i] = f2h(W2[k * 288 + n]);
    else       WT1[i] = f2h(W1[k * 288 + n]);
}

// ---------------------------------------------------------------------------
// Per-edge gains via table interp; writes g4[e] coalesced (float4, edge order)
// ---------------------------------------------------------------------------
__global__ __launch_bounds__(256) void edge_g_tab_kernel(
    const float* __restrict__ pos, const float* __restrict__ edge_attr,
    const int* __restrict__ esrc, const int* __restrict__ edst,
    const float* __restrict__ tab, float* __restrict__ g4)
{
    int e = blockIdx.x * 256 + threadIdx.x;
    if (e >= NE) return;
    int s = esrc[e], d = edst[e];
    float vx = pos[3*s+0] - pos[3*d+0];
    float vy = pos[3*s+1] - pos[3*d+1];
    float vz = pos[3*s+2] - pos[3*d+2];
    float r  = sqrtf(vx*vx + vy*vy + vz*vz);
    float inv = rcpf(r + 1e-12f);
    float ux = vx*inv, uy = vy*inv, uz = vz*inv;

    const float s3 = 1.73205081f, s5 = 2.23606798f, s15 = 3.87298335f;
    float ea[10];
    ea[0] = edge_attr[e];
    ea[1] = 1.0f;
    ea[2] = s3*ux; ea[3] = s3*uy; ea[4] = s3*uz;
    ea[5] = s15*ux*uz; ea[6] = s15*ux*uy;
    ea[7] = s5*(uy*uy - 0.5f*(ux*ux + uz*uz));
    ea[8] = s15*uy*uz;
    ea[9] = 0.5f*s15*(uz*uz - ux*ux);

    float t = r * ((float)TB / 4.0f);
    t = fminf(t, (float)TB - 0.001f);
    int i0 = (int)t;
    float f = t - (float)i0;

    const float* row0 = tab + (size_t)i0 * 40;
    const float* row1 = row0 + 40;
    float g0 = 0, g1 = 0, g2 = 0, g3 = 0;
    #pragma unroll
    for (int k = 0; k < 10; k++) {
        float4 a = *(const float4*)(row0 + k * 4);
        float4 b = *(const float4*)(row1 + k * 4);
        float w = ea[k];
        g0 = fmaf(w, fmaf(f, b.x - a.x, a.x), g0);
        g1 = fmaf(w, fmaf(f, b.y - a.y, a.y), g1);
        g2 = fmaf(w, fmaf(f, b.z - a.z, a.z), g2);
        g3 = fmaf(w, fmaf(f, b.w - a.w, a.w), g3);
    }
    *(float4*)&g4[(size_t)e * 4] =
        make_float4(g0 * 0.25f, g1 * 0.25f, g2 * 0.25f, g3 * 0.25f);
}

// gs[l][p] = { g4[csr[p]][l], bitcast(csr_src[p]) }  — one 8B packed stream
__global__ void permute_g_kernel(const float* __restrict__ g4, const int* __restrict__ csr,
                                 const int* __restrict__ csr_src, float2* __restrict__ gs)
{
    int p = blockIdx.x * 256 + threadIdx.x;
    if (p >= NE) return;
    int e = csr[p];
    float sf = __int_as_float(csr_src[p]);
    float4 g = *(const float4*)&g4[(size_t)e * 4];
    gs[p]          = make_float2(g.x, sf);
    gs[NE + p]     = make_float2(g.y, sf);
    gs[2 * NE + p] = make_float2(g.z, sf);
    gs[3 * NE + p] = make_float2(g.w, sf);
}

// ---------------------------------------------------------------------------
// CSR build: count + hierarchical scan + scatter
// ---------------------------------------------------------------------------
__global__ void count_deg_kernel(const int* __restrict__ edst, int* __restrict__ deg)
{
    int e = blockIdx.x * 256 + threadIdx.x;
    if (e < NE) atomicAdd(&deg[edst[e]], 1);
}

__global__ __launch_bounds__(256) void block_sum_kernel(
    const int* __restrict__ deg, int* __restrict__ bsum)
{
    __shared__ int ws[4];
    int t = threadIdx.x;
    int idx = blockIdx.x * 256 + t;
    int v = (idx < NN) ? deg[idx] : 0;
    #pragma unroll
    for (int off = 1; off < 64; off <<= 1) v += __shfl_xor(v, off);
    if ((t & 63) == 0) ws[t >> 6] = v;
    __syncthreads();
    if (t == 0) bsum[blockIdx.x] = ws[0] + ws[1] + ws[2] + ws[3];
}

__global__ __launch_bounds__(128) void scan_bsum_kernel(
    const int* __restrict__ bsum, int* __restrict__ boff, int* __restrict__ offs)
{
    __shared__ int s[128];
    int t = threadIdx.x;
    s[t] = (t < NBS) ? bsum[t] : 0;
    __syncthreads();
    #pragma unroll
    for (int off = 1; off < 128; off <<= 1) {
        int v = (t >= off) ? s[t - off] : 0;
        __syncthreads();
        s[t] += v;
        __syncthreads();
    }
    if (t < NBS) boff[t] = (t == 0) ? 0 : s[t - 1];
    if (t == 127) offs[NN] = s[127];
}

__global__ __launch_bounds__(256) void scan_local_kernel(
    const int* __restrict__ deg, const int* __restrict__ boff,
    int* __restrict__ offs, int* __restrict__ cur)
{
    __shared__ int s[256];
    int t = threadIdx.x;
    int idx = blockIdx.x * 256 + t;
    int v = (idx < NN) ? deg[idx] : 0;
    s[t] = v;
    __syncthreads();
    #pragma unroll
    for (int off = 1; off < 256; off <<= 1) {
        int u = (t >= off) ? s[t - off] : 0;
        __syncthreads();
        s[t] += u;
        __syncthreads();
    }
    if (idx < NN) {
        int ex = boff[blockIdx.x] + s[t] - v;   // exclusive
        offs[idx] = ex;
        cur[idx] = ex;
    }
}

__global__ void scatter_edges_kernel(const int* __restrict__ edst, const int* __restrict__ esrc,
                                     int* __restrict__ cur, int* __restrict__ csr,
                                     int* __restrict__ csr_src)
{
    int e = blockIdx.x * 256 + threadIdx.x;
    if (e < NE) {
        int slot = atomicAdd(&cur[edst[e]], 1);
        csr[slot] = e;
        csr_src[slot] = esrc[e];
    }
}

// ---------------------------------------------------------------------------
// x0 = fp16(node_input * node_attr)   [NN][8]
// ---------------------------------------------------------------------------
__global__ void x0_kernel(const float* __restrict__ ni, const float* __restrict__ na,
                          ushort* __restrict__ x0)
{
    int n = blockIdx.x * 256 + threadIdx.x;
    if (n >= NN) return;
    float a = na[n];
    float4 v0 = *(const float4*)(ni + n * 8);
    float4 v1 = *(const float4*)(ni + n * 8 + 4);
    uint4 o;
    o.x = pack2h(v0.x * a, v0.y * a);
    o.y = pack2h(v0.z * a, v0.w * a);
    o.z = pack2h(v1.x * a, v1.y * a);
    o.w = pack2h(v1.z * a, v1.w * a);
    *(uint4*)(x0 + n * 8) = o;
}

// ---------------------------------------------------------------------------
// agg for D=8: thread per node, packed (g,src) stream
// ---------------------------------------------------------------------------
__global__ __launch_bounds__(256) void agg8_kernel(
    const ushort* __restrict__ x0, const float2* __restrict__ gs,
    const int* __restrict__ offs, ushort* __restrict__ a0)
{
    int n = blockIdx.x * 256 + threadIdx.x;
    if (n >= NN) return;
    int beg = offs[n], end = offs[n + 1];
    float a[8] = {0,0,0,0,0,0,0,0};
    for (int p = beg; p < end; p++) {
        float2 e = gs[p];
        int s = __float_as_int(e.y);
        F8 f = unpack8h(*(const uint4*)(x0 + (size_t)s * 8));
        float g = e.x;
        a[0] = fmaf(g, f.v0, a[0]); a[1] = fmaf(g, f.v1, a[1]);
        a[2] = fmaf(g, f.v2, a[2]); a[3] = fmaf(g, f.v3, a[3]);
        a[4] = fmaf(g, f.v4, a[4]); a[5] = fmaf(g, f.v5, a[5]);
        a[6] = fmaf(g, f.v6, a[6]); a[7] = fmaf(g, f.v7, a[7]);
    }
    uint4 o;
    o.x = pack2h(a[0], a[1]);
    o.y = pack2h(a[2], a[3]);
    o.z = pack2h(a[4], a[5]);
    o.w = pack2h(a[6], a[7]);
    *(uint4*)(a0 + (size_t)n * 8) = o;
}

// ---------------------------------------------------------------------------
// agg for D=288: thread per (node, 32B chunk) — 18 threads/node.
// 2-edge unroll x 2 loads/edge = 4 independent gathers in flight.
// ---------------------------------------------------------------------------
__global__ __launch_bounds__(256) void agg288_kernel(
    const ushort* __restrict__ xin, const float2* __restrict__ gs,
    const int* __restrict__ offs, ushort* __restrict__ out)
{
    int idx = blockIdx.x * 256 + threadIdx.x;
    if (idx >= NN * 18) return;
    int n = idx / 18, c = idx - n * 18;
    int beg = offs[n], end = offs[n + 1];
    float a0=0,a1=0,a2=0,a3=0,a4=0,a5=0,a6=0,a7=0;
    float b0=0,b1=0,b2=0,b3=0,b4=0,b5=0,b6=0,b7=0;
    const ushort* xb = xin + c * 16;
    int p = beg;
    for (; p + 2 <= end; p += 2) {
        float2 e0 = gs[p];
        float2 e1 = gs[p + 1];
        const ushort* r0 = xb + (size_t)__float_as_int(e0.y) * 288;
        const ushort* r1 = xb + (size_t)__float_as_int(e1.y) * 288;
        uint4 v0a = *(const uint4*)(r0);       // 4 gathers issued
        uint4 v0b = *(const uint4*)(r0 + 8);   // before any unpack
        uint4 v1a = *(const uint4*)(r1);
        uint4 v1b = *(const uint4*)(r1 + 8);
        float g0 = e0.x, g1 = e1.x;
        F8 f;
        f = unpack8h(v0a);
        a0 = fmaf(g0, f.v0, a0); a1 = fmaf(g0, f.v1, a1);
        a2 = fmaf(g0, f.v2, a2); a3 = fmaf(g0, f.v3, a3);
        a4 = fmaf(g0, f.v4, a4); a5 = fmaf(g0, f.v5, a5);
        a6 = fmaf(g0, f.v6, a6); a7 = fmaf(g0, f.v7, a7);
        f = unpack8h(v0b);
        b0 = fmaf(g0, f.v0, b0); b1 = fmaf(g0, f.v1, b1);
        b2 = fmaf(g0, f.v2, b2); b3 = fmaf(g0, f.v3, b3);
        b4 = fmaf(g0, f.v4, b4); b5 = fmaf(g0, f.v5, b5);
        b6 = fmaf(g0, f.v6, b6); b7 = fmaf(g0, f.v7, b7);
        f = unpack8h(v1a);
        a0 = fmaf(g1, f.v0, a0); a1 = fmaf(g1, f.v1, a1);
        a2 = fmaf(g1, f.v2, a2); a3 = fmaf(g1, f.v3, a3);
        a4 = fmaf(g1, f.v4, a4); a5 = fmaf(g1, f.v5, a5);
        a6 = fmaf(g1, f.v6, a6); a7 = fmaf(g1, f.v7, a7);
        f = unpack8h(v1b);
        b0 = fmaf(g1, f.v0, b0); b1 = fmaf(g1, f.v1, b1);
        b2 = fmaf(g1, f.v2, b2); b3 = fmaf(g1, f.v3, b3);
        b4 = fmaf(g1, f.v4, b4); b5 = fmaf(g1, f.v5, b5);
        b6 = fmaf(g1, f.v6, b6); b7 = fmaf(g1, f.v7, b7);
    }
    if (p < end) {
        float2 e0 = gs[p];
        const ushort* r0 = xb + (size_t)__float_as_int(e0.y) * 288;
        uint4 v0a = *(const uint4*)(r0);
        uint4 v0b = *(const uint4*)(r0 + 8);
        float g0 = e0.x;
        F8 f;
        f = unpack8h(v0a);
        a0 = fmaf(g0, f.v0, a0); a1 = fmaf(g0, f.v1, a1);
        a2 = fmaf(g0, f.v2, a2); a3 = fmaf(g0, f.v3, a3);
        a4 = fmaf(g0, f.v4, a4); a5 = fmaf(g0, f.v5, a5);
        a6 = fmaf(g0, f.v6, a6); a7 = fmaf(g0, f.v7, a7);
        f = unpack8h(v0b);
        b0 = fmaf(g0, f.v0, b0); b1 = fmaf(g0, f.v1, b1);
        b2 = fmaf(g0, f.v2, b2); b3 = fmaf(g0, f.v3, b3);
        b4 = fmaf(g0, f.v4, b4); b5 = fmaf(g0, f.v5, b5);
        b6 = fmaf(g0, f.v6, b6); b7 = fmaf(g0, f.v7, b7);
    }
    uint4 o;
    o.x = pack2h(a0, a1);
    o.y = pack2h(a2, a3);
    o.z = pack2h(a4, a5);
    o.w = pack2h(a6, a7);
    ushort* dst = out + (size_t)n * 288 + c * 16;
    *(uint4*)dst = o;
    o.x = pack2h(b0, b1);
    o.y = pack2h(b2, b3);
    o.z = pack2h(b4, b5);
    o.w = pack2h(b6, b7);
    *(uint4*)(dst + 8) = o;
}

// ---------------------------------------------------------------------------
// Layer-0 GEMM: x1 = tanh(a0[NN,8] @ W0[8,288]), fp16 in/out, fp32 W0
// ---------------------------------------------------------------------------
__global__ __launch_bounds__(256) void gemm0_kernel(
    const ushort* __restrict__ a0, const float* __restrict__ W0, ushort* __restrict__ x1)
{
    int idx = blockIdx.x * 256 + threadIdx.x;
    if (idx >= NN * 288) return;
    int n = idx / 288, c = idx - n * 288;
    F8 f = unpack8h(*(const uint4*)(a0 + (size_t)n * 8));
    float h = 0.0f;
    h = fmaf(f.v0, W0[0*288+c], h); h = fmaf(f.v1, W0[1*288+c], h);
    h = fmaf(f.v2, W0[2*288+c], h); h = fmaf(f.v3, W0[3*288+c], h);
    h = fmaf(f.v4, W0[4*288+c], h); h = fmaf(f.v5, W0[5*288+c], h);
    h = fmaf(f.v6, W0[6*288+c], h); h = fmaf(f.v7, W0[7*288+c], h);
    x1[idx] = f2h(fast_tanh(h));
}

// ---------------------------------------------------------------------------
// MFMA GEMM: C = tanh(A[M,288] @ W[288,288]) with BT[n][k] = W[k][n], all fp16.
// 96x96 tile, BK=32, 4 waves (2x2), 48x48 per wave (3x3 fragments).
// ---------------------------------------------------------------------------
__global__ __launch_bounds__(256) void mfma_gemm_kernel(
    const ushort* __restrict__ A, const ushort* __restrict__ BT,
    ushort* __restrict__ C, int M)
{
    __shared__ ushort As[96 * 40];   // row stride 40 ushorts = 80 B (conflict-free)
    __shared__ ushort Bs[96 * 40];
    int tid = threadIdx.x;
    int wave = tid >> 6, lane = tid & 63;
    int wr = wave >> 1, wc = wave & 1;
    int rb = blockIdx.y * 96, cb = blockIdx.x * 96;
    int kq = lane >> 4, rl = lane & 15;

    f32x4 acc[3][3];
    #pragma unroll
    for (int m = 0; m < 3; m++)
        #pragma unroll
        for (int n = 0; n < 3; n++)
            acc[m][n] = (f32x4){0.0f, 0.0f, 0.0f, 0.0f};

    for (int k0 = 0; k0 < 288; k0 += 32) {
        __syncthreads();
        for (int c = tid; c < 384; c += 256) {
            int r = c >> 2, ch = c & 3;
            int gr = rb + r;
            uint4 va = (gr < M) ? *(const uint4*)(A + (size_t)gr * 288 + k0 + ch * 8)
                                : make_uint4(0, 0, 0, 0);
            *(uint4*)&As[r * 40 + ch * 8] = va;
            uint4 vb = *(const uint4*)(BT + (size_t)(cb + r) * 288 + k0 + ch * 8);
            *(uint4*)&Bs[r * 40 + ch * 8] = vb;
        }
        __syncthreads();
        half8 a[3], b[3];
        #pragma unroll
        for (int m = 0; m < 3; m++)
            a[m] = *(const half8*)&As[(wr * 48 + m * 16 + rl) * 40 + kq * 8];
        #pragma unroll
        for (int n = 0; n < 3; n++)
            b[n] = *(const half8*)&Bs[(wc * 48 + n * 16 + rl) * 40 + kq * 8];
        #pragma unroll
        for (int m = 0; m < 3; m++)
            #pragma unroll
            for (int n = 0; n < 3; n++)
                acc[m][n] = __builtin_amdgcn_mfma_f32_16x16x32_f16(a[m], b[n], acc[m][n], 0, 0, 0);
    }
    // epilogue: C/D layout col = lane&15, row = (lane>>4)*4 + q
    #pragma unroll
    for (int m = 0; m < 3; m++) {
        #pragma unroll
        for (int n = 0; n < 3; n++) {
            int col = cb + wc * 48 + n * 16 + rl;
            #pragma unroll
            for (int q = 0; q < 4; q++) {
                int row = rb + wr * 48 + m * 16 + kq * 4 + q;
                if (row < M)
                    C[(size_t)row * 288 + col] = f2h(fast_tanh(acc[m][n][q]));
            }
        }
    }
}

// ---------------------------------------------------------------------------
// Final: y = agg3 @ W3 [288,3]; pooled[g] += y / sqrt(3000). W3 in LDS.
// ---------------------------------------------------------------------------
__global__ __launch_bounds__(256) void final_kernel(
    const ushort* __restrict__ x, const float* __restrict__ W3,
    const int* __restrict__ batch, float* __restrict__ out)
{
    __shared__ float sW[864];
    __shared__ float part[NG * 3];
    int t = threadIdx.x;
    for (int i = t; i < 864; i += 256) sW[i] = W3[i];
    if (t < NG * 3) part[t] = 0.0f;
    __syncthreads();

    int n = blockIdx.x * 256 + t;
    if (n < NN) {
        float a0 = 0, a1 = 0, a2 = 0;
        const ushort* row = x + (size_t)n * 288;
        for (int k = 0; k < 288; k += 8) {
            F8 f = unpack8h(*(const uint4*)(row + k));
            a0 = fmaf(f.v0, sW[(k+0)*3+0], a0); a1 = fmaf(f.v0, sW[(k+0)*3+1], a1); a2 = fmaf(f.v0, sW[(k+0)*3+2], a2);
            a0 = fmaf(f.v1, sW[(k+1)*3+0], a0); a1 = fmaf(f.v1, sW[(k+1)*3+1], a1); a2 = fmaf(f.v1, sW[(k+1)*3+2], a2);
            a0 = fmaf(f.v2, sW[(k+2)*3+0], a0); a1 = fmaf(f.v2, sW[(k+2)*3+1], a1); a2 = fmaf(f.v2, sW[(k+2)*3+2], a2);
            a0 = fmaf(f.v3, sW[(k+3)*3+0], a0); a1 = fmaf(f.v3, sW[(k+3)*3+1], a1); a2 = fmaf(f.v3, sW[(k+3)*3+2], a2);
            a0 = fmaf(f.v4, sW[(k+4)*3+0], a0); a1 = fmaf(f.v4, sW[(k+4)*3+1], a1); a2 = fmaf(f.v4, sW[(k+4)*3+2], a2);
            a0 = fmaf(f.v5, sW[(k+5)*3+0], a0); a1 = fmaf(f.v5, sW[(k+5)*3+1], a1); a2 = fmaf(f.v5, sW[(k+5)*3+2], a2);
            a0 = fmaf(f.v6, sW[(k+6)*3+0], a0); a1 = fmaf(f.v6, sW[(k+6)*3+1], a1); a2 = fmaf(f.v6, sW[(k+6)*3+2], a2);
            a0 = fmaf(f.v7, sW[(k+7)*3+0], a0); a1 = fmaf(f.v7, sW[(k+7)*3+1], a1); a2 = fmaf(f.v7, sW[(k+7)*3+2], a2);
        }
        int g = batch[n];
        atomicAdd(&part[g*3 + 0], a0);
        atomicAdd(&part[g*3 + 1], a1);
        atomicAdd(&part[g*3 + 2], a2);
    }
    __syncthreads();
    if (t < NG * 3) {
        float v = part[t];
        if (v != 0.0f) atomicAdd(&out[t], v * 0.018257419f);
    }
}

// ---------------------------------------------------------------------------
extern "C" void kernel_launch(void* const* d_in, const int* in_sizes, int n_in,
                              void* d_out, int out_size, void* d_ws, size_t ws_size,
                              hipStream_t stream)
{
    const float* pos        = (const float*)d_in[0];
    const float* node_input = (const float*)d_in[1];
    const float* node_attr  = (const float*)d_in[2];
    const float* edge_attr  = (const float*)d_in[3];
    const int*   edge_src   = (const int*)d_in[4];
    const int*   edge_dst   = (const int*)d_in[5];
    const int*   batch      = (const int*)d_in[6];
    const float* fc1        = (const float*)d_in[7];
    const float* b1         = (const float*)d_in[8];
    const float* fc2        = (const float*)d_in[9];
    const float* W0         = (const float*)d_in[10];
    const float* W1         = (const float*)d_in[11];
    const float* W2         = (const float*)d_in[12];
    const float* W3         = (const float*)d_in[13];
    float* out = (float*)d_out;

    // workspace carve-up (256B aligned chunks)
    char* w = (char*)d_ws;
    auto alloc = [&](size_t bytes) { char* p = w; w += (bytes + 255) & ~(size_t)255; return p; };
    float*  g4      = (float*)alloc((size_t)NE * 4 * 4);
    float2* gs      = (float2*)alloc((size_t)NE * 4 * 8);
    int*    deg     = (int*)alloc((size_t)NN * 4);
    int*    offs    = (int*)alloc((size_t)(NN + 1) * 4);
    int*    cur     = (int*)alloc((size_t)NN * 4);
    int*    csr     = (int*)alloc((size_t)NE * 4);
    int*    csr_src = (int*)alloc((size_t)NE * 4);
    float*  tab     = (float*)alloc((size_t)(TB + 1) * 40 * 4);
    int*    bsum    = (int*)alloc(128 * 4);
    int*    boff    = (int*)alloc(128 * 4);
    ushort* w1t     = (ushort*)alloc(288 * 288 * 2);
    ushort* w2t     = (ushort*)alloc(288 * 288 * 2);
    ushort* x0      = (ushort*)alloc((size_t)NN * 8 * 2);
    ushort* a0      = (ushort*)alloc((size_t)NN * 8 * 2);
    ushort* P       = (ushort*)alloc((size_t)NN * 288 * 2);
    ushort* Q       = (ushort*)alloc((size_t)NN * 288 * 2);

    hipMemsetAsync(deg, 0, NN * sizeof(int), stream);
    hipMemsetAsync(d_out, 0, NG * 3 * sizeof(float), stream);

    build_table_kernel<<<((TB + 1) * 16 + 255) / 256, 256, 0, stream>>>(fc1, b1, fc2, tab);
    transw2_kernel<<<648, 256, 0, stream>>>(W1, W2, w1t, w2t);
    x0_kernel<<<(NN + 255) / 256, 256, 0, stream>>>(node_input, node_attr, x0);

    count_deg_kernel<<<1875, 256, 0, stream>>>(edge_dst, deg);
    block_sum_kernel<<<NBS, 256, 0, stream>>>(deg, bsum);
    scan_bsum_kernel<<<1, 128, 0, stream>>>(bsum, boff, offs);
    scan_local_kernel<<<NBS, 256, 0, stream>>>(deg, boff, offs, cur);
    scatter_edges_kernel<<<1875, 256, 0, stream>>>(edge_dst, edge_src, cur, csr, csr_src);

    edge_g_tab_kernel<<<1875, 256, 0, stream>>>(pos, edge_attr, edge_src, edge_dst,
                                                tab, g4);
    permute_g_kernel<<<1875, 256, 0, stream>>>(g4, csr, csr_src, gs);

    // layer 0
    agg8_kernel<<<(NN + 255) / 256, 256, 0, stream>>>(x0, gs, offs, a0);
    gemm0_kernel<<<NN * 288 / 256, 256, 0, stream>>>(a0, W0, P);
    // layer 1
    agg288_kernel<<<(NN * 18 + 255) / 256, 256, 0, stream>>>(P, gs + NE, offs, Q);
    mfma_gemm_kernel<<<dim3(3, 313), 256, 0, stream>>>(Q, w1t, P, NN);
    // layer 2
    agg288_kernel<<<(NN * 18 + 255) / 256, 256, 0, stream>>>(P, gs + 2 * NE, offs, Q);
    mfma_gemm_kernel<<<dim3(3, 313), 256, 0, stream>>>(Q, w2t, P, NN);
    // layer 3
    agg288_kernel<<<(NN * 18 + 255) / 256, 256, 0, stream>>>(P, gs + 3 * NE, offs, Q);
    final_kernel<<<(NN + 255) / 256, 256, 0, stream>>>(Q, W3, batch, out);
}

// Round 14
// 324.376 us; speedup vs baseline: 1.0280x; 1.0280x over previous
//
#include <hip/hip_runtime.h>
#include <math.h>

#define NN 30000
#define NE 480000
#define NG 10
#define TB 8192          // radial table bins over [0, 4.0]
#define NBS 118          // ceil(NN / 256) scan blocks

typedef __attribute__((ext_vector_type(4))) float f32x4;
typedef __attribute__((ext_vector_type(8))) _Float16 half8;

__device__ __forceinline__ float h2f(ushort u) {
    _Float16 h; __builtin_memcpy(&h, &u, 2); return (float)h;
}
__device__ __forceinline__ ushort f2h(float f) {
    _Float16 h = (_Float16)f; ushort u; __builtin_memcpy(&u, &h, 2); return u;
}
__device__ __forceinline__ unsigned int pack2h(float a, float b) {
    return (unsigned int)f2h(a) | ((unsigned int)f2h(b) << 16);
}
struct F8 { float v0,v1,v2,v3,v4,v5,v6,v7; };
__device__ __forceinline__ F8 unpack8h(uint4 v) {
    F8 r;
    r.v0 = h2f((ushort)(v.x & 0xffffu)); r.v1 = h2f((ushort)(v.x >> 16));
    r.v2 = h2f((ushort)(v.y & 0xffffu)); r.v3 = h2f((ushort)(v.y >> 16));
    r.v4 = h2f((ushort)(v.z & 0xffffu)); r.v5 = h2f((ushort)(v.z >> 16));
    r.v6 = h2f((ushort)(v.w & 0xffffu)); r.v7 = h2f((ushort)(v.w >> 16));
    return r;
}
__device__ __forceinline__ float rcpf(float x) { return __builtin_amdgcn_rcpf(x); }
__device__ __forceinline__ float fast_tanh(float x) {
    return 1.0f - 2.0f * rcpf(__expf(2.0f * x) + 1.0f);
}

// ---------------------------------------------------------------------------
// Radial table: tab[i][ii][l] = q_l(r_i)[ii],  r_i = i * 4/TB
// ---------------------------------------------------------------------------
__global__ __launch_bounds__(256) void build_table_kernel(
    const float* __restrict__ fc1, const float* __restrict__ b1,
    const float* __restrict__ fc2, float* __restrict__ tab)
{
    __shared__ float sF1[4000];
    __shared__ float sF2[4000];
    __shared__ float sB[400];
    int tid = threadIdx.x;
    for (int i = tid; i < 4000; i += 256) { sF1[i] = fc1[i]; sF2[i] = fc2[i]; }
    for (int i = tid; i < 400; i += 256) sB[i] = b1[i];
    __syncthreads();

    int id = blockIdx.x * 256 + tid;
    if (id >= (TB + 1) * 16) return;
    int jc = id & 3, l = (id >> 2) & 3, i = id >> 4;
    float r = (float)i * (4.0f / TB);

    float emb[10];
    const float C = 26.6692991f;   // 1.14136 * e^2 * sqrt(10)
    float rr = r * 2.75f;
    #pragma unroll
    for (int k = 0; k < 10; k++) {
        float dd = rr - (float)(k + 1);
        float d2 = dd * dd;
        emb[k] = (d2 < 1.0f) ? C * __expf(-rcpf(1.0f - d2)) : 0.0f;
    }

    const float* __restrict__ F1 = sF1 + l * 1000;   // [10][100]
    const float* __restrict__ Bv = sB + l * 100;
    const float* __restrict__ F2 = sF2 + l * 1000;   // [100][10]
    float q[10] = {0,0,0,0,0,0,0,0,0,0};
    int j0 = jc * 25;
    for (int j = j0; j < j0 + 25; j++) {
        float h = Bv[j];
        #pragma unroll
        for (int k = 0; k < 10; k++) h = fmaf(emb[k], F1[k * 100 + j], h);
        float s = h * rcpf(1.0f + __expf(-h));   // silu
        #pragma unroll
        for (int k = 0; k < 10; k++) q[k] = fmaf(s, F2[j * 10 + k], q[k]);
    }
    #pragma unroll
    for (int k = 0; k < 10; k++) {
        q[k] += __shfl_xor(q[k], 1);
        q[k] += __shfl_xor(q[k], 2);
    }
    if (jc == 0) {
        #pragma unroll
        for (int k = 0; k < 10; k++) tab[(size_t)i * 40 + k * 4 + l] = q[k];
    }
}

// both weight transposes in one launch: WT[n][k] = fp16(W[k][n])
__global__ void transw2_kernel(const float* __restrict__ W1, const float* __restrict__ W2,
                               ushort* __restrict__ WT1, ushort* __restrict__ WT2)
{
    int id = blockIdx.x * 256 + threadIdx.x;
    if (id >= 2 * 288 * 288) return;
    int which = id >= 288 * 288;
    int i = which ? id - 288 * 288 : id;
    int n = i / 288, k = i - n * 288;
    if (which) WT2[i] = f2h(W2[k * 288 + n]);
    else       WT1[i] = f2h(W1[k * 288 + n]);
}

// ---------------------------------------------------------------------------
// Per-edge gains via table interp; writes g4[e] coalesced (float4, edge order)
// ---------------------------------------------------------------------------
__global__ __launch_bounds__(256) void edge_g_tab_kernel(
    const float* __restrict__ pos, const float* __restrict__ edge_attr,
    const int* __restrict__ esrc, const int* __restrict__ edst,
    const float* __restrict__ tab, float* __restrict__ g4)
{
    int e = blockIdx.x * 256 + threadIdx.x;
    if (e >= NE) return;
    int s = esrc[e], d = edst[e];
    float vx = pos[3*s+0] - pos[3*d+0];
    float vy = pos[3*s+1] - pos[3*d+1];
    float vz = pos[3*s+2] - pos[3*d+2];
    float r  = sqrtf(vx*vx + vy*vy + vz*vz);
    float inv = rcpf(r + 1e-12f);
    float ux = vx*inv, uy = vy*inv, uz = vz*inv;

    const float s3 = 1.73205081f, s5 = 2.23606798f, s15 = 3.87298335f;
    float ea[10];
    ea[0] = edge_attr[e];
    ea[1] = 1.0f;
    ea[2] = s3*ux; ea[3] = s3*uy; ea[4] = s3*uz;
    ea[5] = s15*ux*uz; ea[6] = s15*ux*uy;
    ea[7] = s5*(uy*uy - 0.5f*(ux*ux + uz*uz));
    ea[8] = s15*uy*uz;
    ea[9] = 0.5f*s15*(uz*uz - ux*ux);

    float t = r * ((float)TB / 4.0f);
    t = fminf(t, (float)TB - 0.001f);
    int i0 = (int)t;
    float f = t - (float)i0;

    const float* row0 = tab + (size_t)i0 * 40;
    const float* row1 = row0 + 40;
    float g0 = 0, g1 = 0, g2 = 0, g3 = 0;
    #pragma unroll
    for (int k = 0; k < 10; k++) {
        float4 a = *(const float4*)(row0 + k * 4);
        float4 b = *(const float4*)(row1 + k * 4);
        float w = ea[k];
        g0 = fmaf(w, fmaf(f, b.x - a.x, a.x), g0);
        g1 = fmaf(w, fmaf(f, b.y - a.y, a.y), g1);
        g2 = fmaf(w, fmaf(f, b.z - a.z, a.z), g2);
        g3 = fmaf(w, fmaf(f, b.w - a.w, a.w), g3);
    }
    *(float4*)&g4[(size_t)e * 4] =
        make_float4(g0 * 0.25f, g1 * 0.25f, g2 * 0.25f, g3 * 0.25f);
}

// gs[l][p] = { g4[csr[p]][l], bitcast(csr_src[p]) }  — one 8B packed stream
__global__ void permute_g_kernel(const float* __restrict__ g4, const int* __restrict__ csr,
                                 const int* __restrict__ csr_src, float2* __restrict__ gs)
{
    int p = blockIdx.x * 256 + threadIdx.x;
    if (p >= NE) return;
    int e = csr[p];
    float sf = __int_as_float(csr_src[p]);
    float4 g = *(const float4*)&g4[(size_t)e * 4];
    gs[p]          = make_float2(g.x, sf);
    gs[NE + p]     = make_float2(g.y, sf);
    gs[2 * NE + p] = make_float2(g.z, sf);
    gs[3 * NE + p] = make_float2(g.w, sf);
}

// ---------------------------------------------------------------------------
// CSR build: count + hierarchical scan + scatter
// ---------------------------------------------------------------------------
__global__ void count_deg_kernel(const int* __restrict__ edst, int* __restrict__ deg)
{
    int e = blockIdx.x * 256 + threadIdx.x;
    if (e < NE) atomicAdd(&deg[edst[e]], 1);
}

__global__ __launch_bounds__(256) void block_sum_kernel(
    const int* __restrict__ deg, int* __restrict__ bsum)
{
    __shared__ int ws[4];
    int t = threadIdx.x;
    int idx = blockIdx.x * 256 + t;
    int v = (idx < NN) ? deg[idx] : 0;
    #pragma unroll
    for (int off = 1; off < 64; off <<= 1) v += __shfl_xor(v, off);
    if ((t & 63) == 0) ws[t >> 6] = v;
    __syncthreads();
    if (t == 0) bsum[blockIdx.x] = ws[0] + ws[1] + ws[2] + ws[3];
}

__global__ __launch_bounds__(128) void scan_bsum_kernel(
    const int* __restrict__ bsum, int* __restrict__ boff, int* __restrict__ offs)
{
    __shared__ int s[128];
    int t = threadIdx.x;
    s[t] = (t < NBS) ? bsum[t] : 0;
    __syncthreads();
    #pragma unroll
    for (int off = 1; off < 128; off <<= 1) {
        int v = (t >= off) ? s[t - off] : 0;
        __syncthreads();
        s[t] += v;
        __syncthreads();
    }
    if (t < NBS) boff[t] = (t == 0) ? 0 : s[t - 1];
    if (t == 127) offs[NN] = s[127];
}

__global__ __launch_bounds__(256) void scan_local_kernel(
    const int* __restrict__ deg, const int* __restrict__ boff,
    int* __restrict__ offs, int* __restrict__ cur)
{
    __shared__ int s[256];
    int t = threadIdx.x;
    int idx = blockIdx.x * 256 + t;
    int v = (idx < NN) ? deg[idx] : 0;
    s[t] = v;
    __syncthreads();
    #pragma unroll
    for (int off = 1; off < 256; off <<= 1) {
        int u = (t >= off) ? s[t - off] : 0;
        __syncthreads();
        s[t] += u;
        __syncthreads();
    }
    if (idx < NN) {
        int ex = boff[blockIdx.x] + s[t] - v;   // exclusive
        offs[idx] = ex;
        cur[idx] = ex;
    }
}

__global__ void scatter_edges_kernel(const int* __restrict__ edst, const int* __restrict__ esrc,
                                     int* __restrict__ cur, int* __restrict__ csr,
                                     int* __restrict__ csr_src)
{
    int e = blockIdx.x * 256 + threadIdx.x;
    if (e < NE) {
        int slot = atomicAdd(&cur[edst[e]], 1);
        csr[slot] = e;
        csr_src[slot] = esrc[e];
    }
}

// ---------------------------------------------------------------------------
// x0 = fp16(node_input * node_attr)   [NN][8]
// ---------------------------------------------------------------------------
__global__ void x0_kernel(const float* __restrict__ ni, const float* __restrict__ na,
                          ushort* __restrict__ x0)
{
    int n = blockIdx.x * 256 + threadIdx.x;
    if (n >= NN) return;
    float a = na[n];
    float4 v0 = *(const float4*)(ni + n * 8);
    float4 v1 = *(const float4*)(ni + n * 8 + 4);
    uint4 o;
    o.x = pack2h(v0.x * a, v0.y * a);
    o.y = pack2h(v0.z * a, v0.w * a);
    o.z = pack2h(v1.x * a, v1.y * a);
    o.w = pack2h(v1.z * a, v1.w * a);
    *(uint4*)(x0 + n * 8) = o;
}

// ---------------------------------------------------------------------------
// agg for D=8: thread per node, packed (g,src) stream
// ---------------------------------------------------------------------------
__global__ __launch_bounds__(256) void agg8_kernel(
    const ushort* __restrict__ x0, const float2* __restrict__ gs,
    const int* __restrict__ offs, ushort* __restrict__ a0)
{
    int n = blockIdx.x * 256 + threadIdx.x;
    if (n >= NN) return;
    int beg = offs[n], end = offs[n + 1];
    float a[8] = {0,0,0,0,0,0,0,0};
    for (int p = beg; p < end; p++) {
        float2 e = gs[p];
        int s = __float_as_int(e.y);
        F8 f = unpack8h(*(const uint4*)(x0 + (size_t)s * 8));
        float g = e.x;
        a[0] = fmaf(g, f.v0, a[0]); a[1] = fmaf(g, f.v1, a[1]);
        a[2] = fmaf(g, f.v2, a[2]); a[3] = fmaf(g, f.v3, a[3]);
        a[4] = fmaf(g, f.v4, a[4]); a[5] = fmaf(g, f.v5, a[5]);
        a[6] = fmaf(g, f.v6, a[6]); a[7] = fmaf(g, f.v7, a[7]);
    }
    uint4 o;
    o.x = pack2h(a[0], a[1]);
    o.y = pack2h(a[2], a[3]);
    o.z = pack2h(a[4], a[5]);
    o.w = pack2h(a[6], a[7]);
    *(uint4*)(a0 + (size_t)n * 8) = o;
}

// ---------------------------------------------------------------------------
// agg for D=288: thread per (node, 16B chunk) — 36 threads/node.
// 4-edge unroll = 4 independent gathers in flight (2x aggregate MLP vs R11/R12).
// ---------------------------------------------------------------------------
__global__ __launch_bounds__(256) void agg288_kernel(
    const ushort* __restrict__ xin, const float2* __restrict__ gs,
    const int* __restrict__ offs, ushort* __restrict__ out)
{
    int idx = blockIdx.x * 256 + threadIdx.x;
    if (idx >= NN * 36) return;
    int n = idx / 36, c = idx - n * 36;
    int beg = offs[n], end = offs[n + 1];
    float a0=0,a1=0,a2=0,a3=0,a4=0,a5=0,a6=0,a7=0;
    const ushort* xb = xin + c * 8;
    int p = beg;
    for (; p + 4 <= end; p += 4) {
        float2 e0 = gs[p];
        float2 e1 = gs[p + 1];
        float2 e2 = gs[p + 2];
        float2 e3 = gs[p + 3];
        uint4 v0 = *(const uint4*)(xb + (size_t)__float_as_int(e0.y) * 288);
        uint4 v1 = *(const uint4*)(xb + (size_t)__float_as_int(e1.y) * 288);
        uint4 v2 = *(const uint4*)(xb + (size_t)__float_as_int(e2.y) * 288);
        uint4 v3 = *(const uint4*)(xb + (size_t)__float_as_int(e3.y) * 288);
        F8 f;
        float g;
        f = unpack8h(v0); g = e0.x;
        a0 = fmaf(g, f.v0, a0); a1 = fmaf(g, f.v1, a1);
        a2 = fmaf(g, f.v2, a2); a3 = fmaf(g, f.v3, a3);
        a4 = fmaf(g, f.v4, a4); a5 = fmaf(g, f.v5, a5);
        a6 = fmaf(g, f.v6, a6); a7 = fmaf(g, f.v7, a7);
        f = unpack8h(v1); g = e1.x;
        a0 = fmaf(g, f.v0, a0); a1 = fmaf(g, f.v1, a1);
        a2 = fmaf(g, f.v2, a2); a3 = fmaf(g, f.v3, a3);
        a4 = fmaf(g, f.v4, a4); a5 = fmaf(g, f.v5, a5);
        a6 = fmaf(g, f.v6, a6); a7 = fmaf(g, f.v7, a7);
        f = unpack8h(v2); g = e2.x;
        a0 = fmaf(g, f.v0, a0); a1 = fmaf(g, f.v1, a1);
        a2 = fmaf(g, f.v2, a2); a3 = fmaf(g, f.v3, a3);
        a4 = fmaf(g, f.v4, a4); a5 = fmaf(g, f.v5, a5);
        a6 = fmaf(g, f.v6, a6); a7 = fmaf(g, f.v7, a7);
        f = unpack8h(v3); g = e3.x;
        a0 = fmaf(g, f.v0, a0); a1 = fmaf(g, f.v1, a1);
        a2 = fmaf(g, f.v2, a2); a3 = fmaf(g, f.v3, a3);
        a4 = fmaf(g, f.v4, a4); a5 = fmaf(g, f.v5, a5);
        a6 = fmaf(g, f.v6, a6); a7 = fmaf(g, f.v7, a7);
    }
    for (; p < end; p++) {
        float2 e0 = gs[p];
        F8 f = unpack8h(*(const uint4*)(xb + (size_t)__float_as_int(e0.y) * 288));
        float g = e0.x;
        a0 = fmaf(g, f.v0, a0); a1 = fmaf(g, f.v1, a1);
        a2 = fmaf(g, f.v2, a2); a3 = fmaf(g, f.v3, a3);
        a4 = fmaf(g, f.v4, a4); a5 = fmaf(g, f.v5, a5);
        a6 = fmaf(g, f.v6, a6); a7 = fmaf(g, f.v7, a7);
    }
    uint4 o;
    o.x = pack2h(a0, a1);
    o.y = pack2h(a2, a3);
    o.z = pack2h(a4, a5);
    o.w = pack2h(a6, a7);
    *(uint4*)(out + (size_t)idx * 8) = o;
}

// ---------------------------------------------------------------------------
// Layer-0 GEMM: x1 = tanh(a0[NN,8] @ W0[8,288]), fp16 in/out, fp32 W0
// ---------------------------------------------------------------------------
__global__ __launch_bounds__(256) void gemm0_kernel(
    const ushort* __restrict__ a0, const float* __restrict__ W0, ushort* __restrict__ x1)
{
    int idx = blockIdx.x * 256 + threadIdx.x;
    if (idx >= NN * 288) return;
    int n = idx / 288, c = idx - n * 288;
    F8 f = unpack8h(*(const uint4*)(a0 + (size_t)n * 8));
    float h = 0.0f;
    h = fmaf(f.v0, W0[0*288+c], h); h = fmaf(f.v1, W0[1*288+c], h);
    h = fmaf(f.v2, W0[2*288+c], h); h = fmaf(f.v3, W0[3*288+c], h);
    h = fmaf(f.v4, W0[4*288+c], h); h = fmaf(f.v5, W0[5*288+c], h);
    h = fmaf(f.v6, W0[6*288+c], h); h = fmaf(f.v7, W0[7*288+c], h);
    x1[idx] = f2h(fast_tanh(h));
}

// ---------------------------------------------------------------------------
// MFMA GEMM: C = tanh(A[M,288] @ W[288,288]) with BT[n][k] = W[k][n], all fp16.
// 96x96 tile, BK=32, 4 waves (2x2), 48x48 per wave (3x3 fragments).
// ---------------------------------------------------------------------------
__global__ __launch_bounds__(256) void mfma_gemm_kernel(
    const ushort* __restrict__ A, const ushort* __restrict__ BT,
    ushort* __restrict__ C, int M)
{
    __shared__ ushort As[96 * 40];   // row stride 40 ushorts = 80 B (conflict-free)
    __shared__ ushort Bs[96 * 40];
    int tid = threadIdx.x;
    int wave = tid >> 6, lane = tid & 63;
    int wr = wave >> 1, wc = wave & 1;
    int rb = blockIdx.y * 96, cb = blockIdx.x * 96;
    int kq = lane >> 4, rl = lane & 15;

    f32x4 acc[3][3];
    #pragma unroll
    for (int m = 0; m < 3; m++)
        #pragma unroll
        for (int n = 0; n < 3; n++)
            acc[m][n] = (f32x4){0.0f, 0.0f, 0.0f, 0.0f};

    for (int k0 = 0; k0 < 288; k0 += 32) {
        __syncthreads();
        for (int c = tid; c < 384; c += 256) {
            int r = c >> 2, ch = c & 3;
            int gr = rb + r;
            uint4 va = (gr < M) ? *(const uint4*)(A + (size_t)gr * 288 + k0 + ch * 8)
                                : make_uint4(0, 0, 0, 0);
            *(uint4*)&As[r * 40 + ch * 8] = va;
            uint4 vb = *(const uint4*)(BT + (size_t)(cb + r) * 288 + k0 + ch * 8);
            *(uint4*)&Bs[r * 40 + ch * 8] = vb;
        }
        __syncthreads();
        half8 a[3], b[3];
        #pragma unroll
        for (int m = 0; m < 3; m++)
            a[m] = *(const half8*)&As[(wr * 48 + m * 16 + rl) * 40 + kq * 8];
        #pragma unroll
        for (int n = 0; n < 3; n++)
            b[n] = *(const half8*)&Bs[(wc * 48 + n * 16 + rl) * 40 + kq * 8];
        #pragma unroll
        for (int m = 0; m < 3; m++)
            #pragma unroll
            for (int n = 0; n < 3; n++)
                acc[m][n] = __builtin_amdgcn_mfma_f32_16x16x32_f16(a[m], b[n], acc[m][n], 0, 0, 0);
    }
    // epilogue: C/D layout col = lane&15, row = (lane>>4)*4 + q
    #pragma unroll
    for (int m = 0; m < 3; m++) {
        #pragma unroll
        for (int n = 0; n < 3; n++) {
            int col = cb + wc * 48 + n * 16 + rl;
            #pragma unroll
            for (int q = 0; q < 4; q++) {
                int row = rb + wr * 48 + m * 16 + kq * 4 + q;
                if (row < M)
                    C[(size_t)row * 288 + col] = f2h(fast_tanh(acc[m][n][q]));
            }
        }
    }
}

// ---------------------------------------------------------------------------
// Final: y = agg3 @ W3 [288,3]; pooled[g] += y / sqrt(3000). W3 in LDS.
// ---------------------------------------------------------------------------
__global__ __launch_bounds__(256) void final_kernel(
    const ushort* __restrict__ x, const float* __restrict__ W3,
    const int* __restrict__ batch, float* __restrict__ out)
{
    __shared__ float sW[864];
    __shared__ float part[NG * 3];
    int t = threadIdx.x;
    for (int i = t; i < 864; i += 256) sW[i] = W3[i];
    if (t < NG * 3) part[t] = 0.0f;
    __syncthreads();

    int n = blockIdx.x * 256 + t;
    if (n < NN) {
        float a0 = 0, a1 = 0, a2 = 0;
        const ushort* row = x + (size_t)n * 288;
        for (int k = 0; k < 288; k += 8) {
            F8 f = unpack8h(*(const uint4*)(row + k));
            a0 = fmaf(f.v0, sW[(k+0)*3+0], a0); a1 = fmaf(f.v0, sW[(k+0)*3+1], a1); a2 = fmaf(f.v0, sW[(k+0)*3+2], a2);
            a0 = fmaf(f.v1, sW[(k+1)*3+0], a0); a1 = fmaf(f.v1, sW[(k+1)*3+1], a1); a2 = fmaf(f.v1, sW[(k+1)*3+2], a2);
            a0 = fmaf(f.v2, sW[(k+2)*3+0], a0); a1 = fmaf(f.v2, sW[(k+2)*3+1], a1); a2 = fmaf(f.v2, sW[(k+2)*3+2], a2);
            a0 = fmaf(f.v3, sW[(k+3)*3+0], a0); a1 = fmaf(f.v3, sW[(k+3)*3+1], a1); a2 = fmaf(f.v3, sW[(k+3)*3+2], a2);
            a0 = fmaf(f.v4, sW[(k+4)*3+0], a0); a1 = fmaf(f.v4, sW[(k+4)*3+1], a1); a2 = fmaf(f.v4, sW[(k+4)*3+2], a2);
            a0 = fmaf(f.v5, sW[(k+5)*3+0], a0); a1 = fmaf(f.v5, sW[(k+5)*3+1], a1); a2 = fmaf(f.v5, sW[(k+5)*3+2], a2);
            a0 = fmaf(f.v6, sW[(k+6)*3+0], a0); a1 = fmaf(f.v6, sW[(k+6)*3+1], a1); a2 = fmaf(f.v6, sW[(k+6)*3+2], a2);
            a0 = fmaf(f.v7, sW[(k+7)*3+0], a0); a1 = fmaf(f.v7, sW[(k+7)*3+1], a1); a2 = fmaf(f.v7, sW[(k+7)*3+2], a2);
        }
        int g = batch[n];
        atomicAdd(&part[g*3 + 0], a0);
        atomicAdd(&part[g*3 + 1], a1);
        atomicAdd(&part[g*3 + 2], a2);
    }
    __syncthreads();
    if (t < NG * 3) {
        float v = part[t];
        if (v != 0.0f) atomicAdd(&out[t], v * 0.018257419f);
    }
}

// ---------------------------------------------------------------------------
extern "C" void kernel_launch(void* const* d_in, const int* in_sizes, int n_in,
                              void* d_out, int out_size, void* d_ws, size_t ws_size,
                              hipStream_t stream)
{
    const float* pos        = (const float*)d_in[0];
    const float* node_input = (const float*)d_in[1];
    const float* node_attr  = (const float*)d_in[2];
    const float* edge_attr  = (const float*)d_in[3];
    const int*   edge_src   = (const int*)d_in[4];
    const int*   edge_dst   = (const int*)d_in[5];
    const int*   batch      = (const int*)d_in[6];
    const float* fc1        = (const float*)d_in[7];
    const float* b1         = (const float*)d_in[8];
    const float* fc2        = (const float*)d_in[9];
    const float* W0         = (const float*)d_in[10];
    const float* W1         = (const float*)d_in[11];
    const float* W2         = (const float*)d_in[12];
    const float* W3         = (const float*)d_in[13];
    float* out = (float*)d_out;

    // workspace carve-up (256B aligned chunks)
    char* w = (char*)d_ws;
    auto alloc = [&](size_t bytes) { char* p = w; w += (bytes + 255) & ~(size_t)255; return p; };
    float*  g4      = (float*)alloc((size_t)NE * 4 * 4);
    float2* gs      = (float2*)alloc((size_t)NE * 4 * 8);
    int*    deg     = (int*)alloc((size_t)NN * 4);
    int*    offs    = (int*)alloc((size_t)(NN + 1) * 4);
    int*    cur     = (int*)alloc((size_t)NN * 4);
    int*    csr     = (int*)alloc((size_t)NE * 4);
    int*    csr_src = (int*)alloc((size_t)NE * 4);
    float*  tab     = (float*)alloc((size_t)(TB + 1) * 40 * 4);
    int*    bsum    = (int*)alloc(128 * 4);
    int*    boff    = (int*)alloc(128 * 4);
    ushort* w1t     = (ushort*)alloc(288 * 288 * 2);
    ushort* w2t     = (ushort*)alloc(288 * 288 * 2);
    ushort* x0      = (ushort*)alloc((size_t)NN * 8 * 2);
    ushort* a0      = (ushort*)alloc((size_t)NN * 8 * 2);
    ushort* P       = (ushort*)alloc((size_t)NN * 288 * 2);
    ushort* Q       = (ushort*)alloc((size_t)NN * 288 * 2);

    hipMemsetAsync(deg, 0, NN * sizeof(int), stream);
    hipMemsetAsync(d_out, 0, NG * 3 * sizeof(float), stream);

    build_table_kernel<<<((TB + 1) * 16 + 255) / 256, 256, 0, stream>>>(fc1, b1, fc2, tab);
    transw2_kernel<<<648, 256, 0, stream>>>(W1, W2, w1t, w2t);
    x0_kernel<<<(NN + 255) / 256, 256, 0, stream>>>(node_input, node_attr, x0);

    count_deg_kernel<<<1875, 256, 0, stream>>>(edge_dst, deg);
    block_sum_kernel<<<NBS, 256, 0, stream>>>(deg, bsum);
    scan_bsum_kernel<<<1, 128, 0, stream>>>(bsum, boff, offs);
    scan_local_kernel<<<NBS, 256, 0, stream>>>(deg, boff, offs, cur);
    scatter_edges_kernel<<<1875, 256, 0, stream>>>(edge_dst, edge_src, cur, csr, csr_src);

    edge_g_tab_kernel<<<1875, 256, 0, stream>>>(pos, edge_attr, edge_src, edge_dst,
                                                tab, g4);
    permute_g_kernel<<<1875, 256, 0, stream>>>(g4, csr, csr_src, gs);

    // layer 0
    agg8_kernel<<<(NN + 255) / 256, 256, 0, stream>>>(x0, gs, offs, a0);
    gemm0_kernel<<<NN * 288 / 256, 256, 0, stream>>>(a0, W0, P);
    // layer 1
    agg288_kernel<<<(NN * 36 + 255) / 256, 256, 0, stream>>>(P, gs + NE, offs, Q);
    mfma_gemm_kernel<<<dim3(3, 313), 256, 0, stream>>>(Q, w1t, P, NN);
    // layer 2
    agg288_kernel<<<(NN * 36 + 255) / 256, 256, 0, stream>>>(P, gs + 2 * NE, offs, Q);
    mfma_gemm_kernel<<<dim3(3, 313), 256, 0, stream>>>(Q, w2t, P, NN);
    // layer 3
    agg288_kernel<<<(NN * 36 + 255) / 256, 256, 0, stream>>>(P, gs + 3 * NE, offs, Q);
    final_kernel<<<(NN + 255) / 256, 256, 0, stream>>>(Q, W3, batch, out);
}